// Round 4
// baseline (434.976 us; speedup 1.0000x reference)
//
#include <hip/hip_runtime.h>
#include <math.h>

#define N_NODES 50000
#define N_EDGES 800000
#define ET (N_EDGES + N_NODES)   // 850000 incl. self-loops
#define KD 128
#define Z 32
#define NBS ((N_NODES + 1023) / 1024)

static __device__ __forceinline__ float lrelu(float x){ return x > 0.f ? x : 0.2f*x; }

// ---------- CSR build ----------
__global__ __launch_bounds__(256) void hist_kernel(const int* __restrict__ edges, int* __restrict__ deg){
  int k = blockIdx.x*256 + threadIdx.x;
  if(k >= ET) return;
  int d = (k < N_EDGES) ? edges[N_EDGES + k] : (k - N_EDGES);
  atomicAdd(&deg[d], 1);
}

__global__ __launch_bounds__(256) void scan1_kernel(const int* __restrict__ deg, int* __restrict__ bsum){
  int b = blockIdx.x, t = threadIdx.x;
  int base = b*1024 + t*4;
  int s = 0;
  #pragma unroll
  for(int i=0;i<4;i++){ int n = base+i; if(n < N_NODES) s += deg[n]; }
  for(int off=32; off; off>>=1) s += __shfl_xor(s, off);
  __shared__ int ws[4];
  if((t&63)==0) ws[t>>6] = s;
  __syncthreads();
  if(t==0) bsum[b] = ws[0]+ws[1]+ws[2]+ws[3];
}

__global__ __launch_bounds__(64) void scan2_kernel(const int* __restrict__ bsum, int* __restrict__ bpre){
  int t = threadIdx.x;
  int x = (t < NBS) ? bsum[t] : 0;
  int v = x;
  for(int off=1; off<64; off<<=1){
    int u = __shfl_up(v, off);
    if(t >= off) v += u;
  }
  if(t < NBS) bpre[t] = v - x;
}

__global__ __launch_bounds__(256) void scan3_kernel(const int* __restrict__ deg, const int* __restrict__ bpre,
                                                    int* __restrict__ rowptr, int* __restrict__ cursor){
  int b = blockIdx.x, t = threadIdx.x;
  int lane = t & 63, wv = t >> 6;
  int base = b*1024 + t*4;
  int d[4]; int s = 0;
  #pragma unroll
  for(int i=0;i<4;i++){ int n = base+i; d[i] = (n < N_NODES) ? deg[n] : 0; s += d[i]; }
  int v = s;
  for(int off=1; off<64; off<<=1){
    int u = __shfl_up(v, off);
    if(lane >= off) v += u;
  }
  int texcl = v - s;
  __shared__ int wtot[4];
  if(lane == 63) wtot[wv] = v;
  __syncthreads();
  int woff = 0;
  for(int i=0;i<wv;i++) woff += wtot[i];
  int run = bpre[b] + woff + texcl;
  #pragma unroll
  for(int i=0;i<4;i++){
    int n = base+i;
    if(n < N_NODES){ rowptr[n] = run; cursor[n] = run; run += d[i]; }
  }
  if(b == 0 && t == 0) rowptr[N_NODES] = ET;
}

__global__ __launch_bounds__(256) void scatter_kernel(const int* __restrict__ edges, int* __restrict__ cursor,
                                                      int* __restrict__ esrc, int* __restrict__ edst){
  int k = blockIdx.x*256 + threadIdx.x;
  if(k >= ET) return;
  int s, d;
  if(k < N_EDGES){ s = edges[k]; d = edges[N_EDGES+k]; } else { s = d = k - N_EDGES; }
  int pos = atomicAdd(&cursor[d], 1);
  esrc[pos] = s;
  edst[pos] = d;
}

// ---------- dense matmul ----------
template<int OC, int NR>
__global__ __launch_bounds__(256) void mm_kernel(const float* __restrict__ X,
                                                 const float* __restrict__ Wa,
                                                 const float* __restrict__ Wb, int splitRow,
                                                 float* __restrict__ out){
  constexpr int G  = OC/4;
  constexpr int RG = 256/G;
  static_assert(NR == RG*4, "rows per block mismatch");
  __shared__ __align__(16) float Wl[OC*KD];

  for(int idx = threadIdx.x; idx < OC*KD; idx += 256){
    int j = idx >> 7;
    int k = idx & 127;
    float v = (j < splitRow) ? Wa[j*KD + k] : Wb[(j-splitRow)*KD + k];
    int k4 = k >> 2, u = k & 3;
    Wl[j*KD + 4*(k4 ^ (j & 31)) + u] = v;
  }
  __syncthreads();

  int cx = threadIdx.x % G;
  int ry = threadIdx.x / G;
  int row0 = blockIdx.x * NR + ry*4;

  float acc[4][4];
  #pragma unroll
  for(int i=0;i<4;i++)
    #pragma unroll
    for(int j=0;j<4;j++) acc[i][j] = 0.f;

  for(int k4 = 0; k4 < KD/4; k4++){
    float4 xv[4];
    #pragma unroll
    for(int i=0;i<4;i++){
      int r = row0 + i; r = r < N_NODES ? r : N_NODES-1;
      xv[i] = *(const float4*)(X + (size_t)r*KD + 4*k4);
    }
    #pragma unroll
    for(int jj=0;jj<4;jj++){
      int c = cx + jj*G;
      float4 wv = *(const float4*)(&Wl[c*KD + 4*(k4 ^ (c & 31))]);
      #pragma unroll
      for(int i=0;i<4;i++){
        acc[i][jj] += xv[i].x*wv.x;
        acc[i][jj] += xv[i].y*wv.y;
        acc[i][jj] += xv[i].z*wv.z;
        acc[i][jj] += xv[i].w*wv.w;
      }
    }
  }

  #pragma unroll
  for(int i=0;i<4;i++){
    int r = row0 + i;
    if(r < N_NODES){
      #pragma unroll
      for(int jj=0;jj<4;jj++) out[(size_t)r*OC + cx + jj*G] = acc[i][jj];
    }
  }
}

// ---------- attention coefficient dots ----------
__global__ __launch_bounds__(256) void alpha1_kernel(const float* __restrict__ xp,
                                                     const float* __restrict__ asv, const float* __restrict__ adv,
                                                     float* __restrict__ as1, float* __restrict__ ad1){
  int node = blockIdx.x*4 + (threadIdx.x>>6);
  int l = threadIdx.x & 63;
  if(node >= N_NODES) return;
  float x0 = xp[(size_t)node*128 + l], x1 = xp[(size_t)node*128 + 64 + l];
  float s0 = x0*asv[l], s1 = x1*asv[64+l];
  float d0 = x0*adv[l], d1 = x1*adv[64+l];
  for(int off=32; off; off>>=1){
    s0 += __shfl_xor(s0, off); s1 += __shfl_xor(s1, off);
    d0 += __shfl_xor(d0, off); d1 += __shfl_xor(d1, off);
  }
  if(l == 0){ as1[node*2]=s0; as1[node*2+1]=s1; ad1[node*2]=d0; ad1[node*2+1]=d1; }
}

__global__ __launch_bounds__(256) void alpha2_kernel(const float* __restrict__ xp2,
                                                     const float* __restrict__ asmu, const float* __restrict__ admu,
                                                     const float* __restrict__ asst, const float* __restrict__ adst,
                                                     float* __restrict__ as2, float* __restrict__ ad2){
  int node = blockIdx.x*4 + (threadIdx.x>>6);
  int l = threadIdx.x & 63;
  if(node >= N_NODES) return;
  int half = l >> 5, c = l & 31;
  float v = xp2[(size_t)node*64 + l];
  float sp = v * (half ? asst[c] : asmu[c]);
  float dp = v * (half ? adst[c] : admu[c]);
  for(int off=16; off; off>>=1){ sp += __shfl_xor(sp, off); dp += __shfl_xor(dp, off); }
  if(c == 0){ as2[node*2+half] = sp; ad2[node*2+half] = dp; }
}

// ---------- per-edge softmax weights (no max-shift: e bounded, exp-safe) ----------
__global__ __launch_bounds__(256) void wcalc_kernel(const int* __restrict__ esrc, const int* __restrict__ edst,
                                                    const float* __restrict__ asv, const float* __restrict__ adv,
                                                    float2* __restrict__ wbuf){
  int i = blockIdx.x*256 + threadIdx.x;
  if(i >= ET) return;
  int s = esrc[i], d = edst[i];
  float2 a = ((const float2*)asv)[s];
  float2 b = ((const float2*)adv)[d];
  float2 w;
  w.x = __expf(lrelu(a.x + b.x));
  w.y = __expf(lrelu(a.y + b.y));
  wbuf[i] = w;
}

// ---------- edge aggregation, layer 1 (precomputed weights; unroll-8) ----------
__global__ __launch_bounds__(256) void agg1_kernel(const int* __restrict__ rowptr, const int* __restrict__ esrc,
                                                   const float2* __restrict__ wbuf, const float* __restrict__ xp,
                                                   const float* __restrict__ b1, float* __restrict__ h){
  int node = blockIdx.x*4 + (threadIdx.x>>6);
  int l = threadIdx.x & 63;
  if(node >= N_NODES) return;
  int beg = rowptr[node], end = rowptr[node+1];
  const float2* xpv = (const float2*)xp;
  float accx = 0.f, accy = 0.f, s0 = 0.f, s1 = 0.f;
  int n = end - beg;
  int nq = n & ~7;
  for(int q = 0; q < nq; q += 8){
    int e[8]; float2 w[8], xv[8];
    #pragma unroll
    for(int j=0;j<8;j++) e[j] = esrc[beg+q+j];
    #pragma unroll
    for(int j=0;j<8;j++) w[j] = wbuf[beg+q+j];
    #pragma unroll
    for(int j=0;j<8;j++) xv[j] = xpv[(size_t)e[j]*64 + l];
    #pragma unroll
    for(int j=0;j<8;j++){
      s0 += w[j].x; s1 += w[j].y;
      float ww = (l < 32) ? w[j].x : w[j].y;
      accx += ww * xv[j].x;
      accy += ww * xv[j].y;
    }
  }
  for(int i = beg + nq; i < end; i++){
    int s = esrc[i];
    float2 w = wbuf[i];
    s0 += w.x; s1 += w.y;
    float2 xv = xpv[(size_t)s*64 + l];
    float ww = (l < 32) ? w.x : w.y;
    accx += ww * xv.x;
    accy += ww * xv.y;
  }
  float sd = (l < 32) ? s0 : s1;
  float2 bb = ((const float2*)b1)[l];
  float2 r;
  r.x = fmaxf(accx/sd + bb.x, 0.f);
  r.y = fmaxf(accy/sd + bb.y, 0.f);
  ((float2*)h)[(size_t)node*64 + l] = r;
}

// ---------- edge aggregation, layer 2 (mu+std fused; precomputed weights; unroll-8) ----------
__global__ __launch_bounds__(256) void agg2_kernel(const int* __restrict__ rowptr, const int* __restrict__ esrc,
                                                   const float2* __restrict__ wbuf, const float* __restrict__ xp2,
                                                   const float* __restrict__ bmu, const float* __restrict__ bst,
                                                   float* __restrict__ out){
  int node = blockIdx.x*4 + (threadIdx.x>>6);
  int l = threadIdx.x & 63;
  if(node >= N_NODES) return;
  int half = l >> 5, c = l & 31;
  int beg = rowptr[node], end = rowptr[node+1];
  float acc = 0.f, ssum = 0.f;
  int n = end - beg;
  int nq = n & ~7;
  for(int q = 0; q < nq; q += 8){
    int e[8]; float2 w[8]; float xv[8];
    #pragma unroll
    for(int j=0;j<8;j++) e[j] = esrc[beg+q+j];
    #pragma unroll
    for(int j=0;j<8;j++) w[j] = wbuf[beg+q+j];
    #pragma unroll
    for(int j=0;j<8;j++) xv[j] = xp2[(size_t)e[j]*64 + l];
    #pragma unroll
    for(int j=0;j<8;j++){
      float ww = half ? w[j].y : w[j].x;
      ssum += ww;
      acc  += ww * xv[j];
    }
  }
  for(int i = beg + nq; i < end; i++){
    int s = esrc[i];
    float2 w = wbuf[i];
    float ww = half ? w.y : w.x;
    ssum += ww;
    acc += ww * xp2[(size_t)s*64 + l];
  }
  float r = acc/ssum + (half ? bst[c] : bmu[c]);
  out[(half ? (size_t)N_NODES*Z : 0) + (size_t)node*Z + c] = r;
}

extern "C" void kernel_launch(void* const* d_in, const int* in_sizes, int n_in,
                              void* d_out, int out_size, void* d_ws, size_t ws_size,
                              hipStream_t stream){
  const float* x    = (const float*)d_in[0];
  const int*   edges= (const int*)d_in[1];
  const float* W1   = (const float*)d_in[2];
  const float* as1v = (const float*)d_in[3];
  const float* ad1v = (const float*)d_in[4];
  const float* b1   = (const float*)d_in[5];
  const float* Wmu  = (const float*)d_in[6];
  const float* asmu = (const float*)d_in[7];
  const float* admu = (const float*)d_in[8];
  const float* bmu  = (const float*)d_in[9];
  const float* Wst  = (const float*)d_in[10];
  const float* asst = (const float*)d_in[11];
  const float* adst = (const float*)d_in[12];
  const float* bst  = (const float*)d_in[13];
  float* out = (float*)d_out;

  char* p = (char*)d_ws;
  auto alloc = [&](size_t bytes)->char*{ char* r = p; p += (bytes + 255) & ~size_t(255); return r; };
  int*   deg    = (int*)  alloc((size_t)N_NODES*4);
  int*   rowptr = (int*)  alloc((size_t)(N_NODES+1)*4);
  int*   cursor = (int*)  alloc((size_t)N_NODES*4);
  int*   esrc   = (int*)  alloc((size_t)ET*4);
  int*   edst   = (int*)  alloc((size_t)ET*4);
  int*   bsum   = (int*)  alloc((size_t)NBS*4);
  int*   bpre   = (int*)  alloc((size_t)NBS*4);
  float* xp1    = (float*)alloc((size_t)N_NODES*128*4);
  float* as1    = (float*)alloc((size_t)N_NODES*2*4);
  float* ad1    = (float*)alloc((size_t)N_NODES*2*4);
  float* h      = (float*)alloc((size_t)N_NODES*128*4);
  float2* wbuf  = (float2*)alloc((size_t)ET*8);        // reused for layer 2
  float* as2    = (float*)alloc((size_t)N_NODES*2*4);
  float* ad2    = (float*)alloc((size_t)N_NODES*2*4);
  float* xp2    = xp1;                                  // xp1 dead after agg1

  hipMemsetAsync(deg, 0, (size_t)N_NODES*4, stream);
  hist_kernel   <<<(ET+255)/256, 256, 0, stream>>>(edges, deg);
  scan1_kernel  <<<NBS, 256, 0, stream>>>(deg, bsum);
  scan2_kernel  <<<1, 64, 0, stream>>>(bsum, bpre);
  scan3_kernel  <<<NBS, 256, 0, stream>>>(deg, bpre, rowptr, cursor);
  scatter_kernel<<<(ET+255)/256, 256, 0, stream>>>(edges, cursor, esrc, edst);

  mm_kernel<128,32><<<(N_NODES+31)/32, 256, 0, stream>>>(x, W1, W1, 128, xp1);
  alpha1_kernel<<<(N_NODES+3)/4, 256, 0, stream>>>(xp1, as1v, ad1v, as1, ad1);
  wcalc_kernel <<<(ET+255)/256, 256, 0, stream>>>(esrc, edst, as1, ad1, wbuf);
  agg1_kernel  <<<(N_NODES+3)/4, 256, 0, stream>>>(rowptr, esrc, wbuf, xp1, b1, h);

  mm_kernel<64,64><<<(N_NODES+63)/64, 256, 0, stream>>>(h, Wmu, Wst, 32, xp2);
  alpha2_kernel<<<(N_NODES+3)/4, 256, 0, stream>>>(xp2, asmu, admu, asst, adst, as2, ad2);
  wcalc_kernel <<<(ET+255)/256, 256, 0, stream>>>(esrc, edst, as2, ad2, wbuf);
  agg2_kernel  <<<(N_NODES+3)/4, 256, 0, stream>>>(rowptr, esrc, wbuf, xp2, bmu, bst, out);
}

// Round 5
// 397.931 us; speedup vs baseline: 1.0931x; 1.0931x over previous
//
#include <hip/hip_runtime.h>
#include <math.h>

#define N_NODES 50000
#define N_EDGES 800000
#define ET (N_EDGES + N_NODES)   // 850000 incl. self-loops
#define KD 128
#define Z 32
#define NBS ((N_NODES + 1023) / 1024)

static __device__ __forceinline__ float lrelu(float x){ return x > 0.f ? x : 0.2f*x; }

// ---------- CSR build ----------
__global__ __launch_bounds__(256) void hist_kernel(const int* __restrict__ edges, int* __restrict__ deg){
  int k = blockIdx.x*256 + threadIdx.x;
  if(k >= ET) return;
  int d = (k < N_EDGES) ? edges[N_EDGES + k] : (k - N_EDGES);
  atomicAdd(&deg[d], 1);
}

__global__ __launch_bounds__(256) void scan1_kernel(const int* __restrict__ deg, int* __restrict__ bsum){
  int b = blockIdx.x, t = threadIdx.x;
  int base = b*1024 + t*4;
  int s = 0;
  #pragma unroll
  for(int i=0;i<4;i++){ int n = base+i; if(n < N_NODES) s += deg[n]; }
  for(int off=32; off; off>>=1) s += __shfl_xor(s, off);
  __shared__ int ws[4];
  if((t&63)==0) ws[t>>6] = s;
  __syncthreads();
  if(t==0) bsum[b] = ws[0]+ws[1]+ws[2]+ws[3];
}

__global__ __launch_bounds__(64) void scan2_kernel(const int* __restrict__ bsum, int* __restrict__ bpre){
  int t = threadIdx.x;
  int x = (t < NBS) ? bsum[t] : 0;
  int v = x;
  for(int off=1; off<64; off<<=1){
    int u = __shfl_up(v, off);
    if(t >= off) v += u;
  }
  if(t < NBS) bpre[t] = v - x;
}

__global__ __launch_bounds__(256) void scan3_kernel(const int* __restrict__ deg, const int* __restrict__ bpre,
                                                    int* __restrict__ rowptr, int* __restrict__ cursor){
  int b = blockIdx.x, t = threadIdx.x;
  int lane = t & 63, wv = t >> 6;
  int base = b*1024 + t*4;
  int d[4]; int s = 0;
  #pragma unroll
  for(int i=0;i<4;i++){ int n = base+i; d[i] = (n < N_NODES) ? deg[n] : 0; s += d[i]; }
  int v = s;
  for(int off=1; off<64; off<<=1){
    int u = __shfl_up(v, off);
    if(lane >= off) v += u;
  }
  int texcl = v - s;
  __shared__ int wtot[4];
  if(lane == 63) wtot[wv] = v;
  __syncthreads();
  int woff = 0;
  for(int i=0;i<wv;i++) woff += wtot[i];
  int run = bpre[b] + woff + texcl;
  #pragma unroll
  for(int i=0;i<4;i++){
    int n = base+i;
    if(n < N_NODES){ rowptr[n] = run; cursor[n] = run; run += d[i]; }
  }
  if(b == 0 && t == 0) rowptr[N_NODES] = ET;
}

__global__ __launch_bounds__(256) void scatter_kernel(const int* __restrict__ edges, int* __restrict__ cursor,
                                                      int* __restrict__ esrc, int* __restrict__ edst){
  int k = blockIdx.x*256 + threadIdx.x;
  if(k >= ET) return;
  int s, d;
  if(k < N_EDGES){ s = edges[k]; d = edges[N_EDGES+k]; } else { s = d = k - N_EDGES; }
  int pos = atomicAdd(&cursor[d], 1);
  esrc[pos] = s;
  edst[pos] = d;
}

// ---------- dense matmul ----------
template<int OC, int NR>
__global__ __launch_bounds__(256) void mm_kernel(const float* __restrict__ X,
                                                 const float* __restrict__ Wa,
                                                 const float* __restrict__ Wb, int splitRow,
                                                 float* __restrict__ out){
  constexpr int G  = OC/4;
  constexpr int RG = 256/G;
  static_assert(NR == RG*4, "rows per block mismatch");
  __shared__ __align__(16) float Wl[OC*KD];

  for(int idx = threadIdx.x; idx < OC*KD; idx += 256){
    int j = idx >> 7;
    int k = idx & 127;
    float v = (j < splitRow) ? Wa[j*KD + k] : Wb[(j-splitRow)*KD + k];
    int k4 = k >> 2, u = k & 3;
    Wl[j*KD + 4*(k4 ^ (j & 31)) + u] = v;
  }
  __syncthreads();

  int cx = threadIdx.x % G;
  int ry = threadIdx.x / G;
  int row0 = blockIdx.x * NR + ry*4;

  float acc[4][4];
  #pragma unroll
  for(int i=0;i<4;i++)
    #pragma unroll
    for(int j=0;j<4;j++) acc[i][j] = 0.f;

  for(int k4 = 0; k4 < KD/4; k4++){
    float4 xv[4];
    #pragma unroll
    for(int i=0;i<4;i++){
      int r = row0 + i; r = r < N_NODES ? r : N_NODES-1;
      xv[i] = *(const float4*)(X + (size_t)r*KD + 4*k4);
    }
    #pragma unroll
    for(int jj=0;jj<4;jj++){
      int c = cx + jj*G;
      float4 wv = *(const float4*)(&Wl[c*KD + 4*(k4 ^ (c & 31))]);
      #pragma unroll
      for(int i=0;i<4;i++){
        acc[i][jj] += xv[i].x*wv.x;
        acc[i][jj] += xv[i].y*wv.y;
        acc[i][jj] += xv[i].z*wv.z;
        acc[i][jj] += xv[i].w*wv.w;
      }
    }
  }

  #pragma unroll
  for(int i=0;i<4;i++){
    int r = row0 + i;
    if(r < N_NODES){
      #pragma unroll
      for(int jj=0;jj<4;jj++) out[(size_t)r*OC + cx + jj*G] = acc[i][jj];
    }
  }
}

// ---------- attention coefficient dots ----------
__global__ __launch_bounds__(256) void alpha1_kernel(const float* __restrict__ xp,
                                                     const float* __restrict__ asv, const float* __restrict__ adv,
                                                     float* __restrict__ as1, float* __restrict__ ad1){
  int node = blockIdx.x*4 + (threadIdx.x>>6);
  int l = threadIdx.x & 63;
  if(node >= N_NODES) return;
  float x0 = xp[(size_t)node*128 + l], x1 = xp[(size_t)node*128 + 64 + l];
  float s0 = x0*asv[l], s1 = x1*asv[64+l];
  float d0 = x0*adv[l], d1 = x1*adv[64+l];
  for(int off=32; off; off>>=1){
    s0 += __shfl_xor(s0, off); s1 += __shfl_xor(s1, off);
    d0 += __shfl_xor(d0, off); d1 += __shfl_xor(d1, off);
  }
  if(l == 0){ as1[node*2]=s0; as1[node*2+1]=s1; ad1[node*2]=d0; ad1[node*2+1]=d1; }
}

__global__ __launch_bounds__(256) void alpha2_kernel(const float* __restrict__ xp2,
                                                     const float* __restrict__ asmu, const float* __restrict__ admu,
                                                     const float* __restrict__ asst, const float* __restrict__ adst,
                                                     float* __restrict__ as2, float* __restrict__ ad2){
  int node = blockIdx.x*4 + (threadIdx.x>>6);
  int l = threadIdx.x & 63;
  if(node >= N_NODES) return;
  int half = l >> 5, c = l & 31;
  float v = xp2[(size_t)node*64 + l];
  float sp = v * (half ? asst[c] : asmu[c]);
  float dp = v * (half ? adst[c] : admu[c]);
  for(int off=16; off; off>>=1){ sp += __shfl_xor(sp, off); dp += __shfl_xor(dp, off); }
  if(c == 0){ as2[node*2+half] = sp; ad2[node*2+half] = dp; }
}

// ---------- per-edge softmax weights (no max-shift: e bounded, exp-safe) ----------
__global__ __launch_bounds__(256) void wcalc_kernel(const int* __restrict__ esrc, const int* __restrict__ edst,
                                                    const float* __restrict__ asv, const float* __restrict__ adv,
                                                    float2* __restrict__ wbuf){
  int i = blockIdx.x*256 + threadIdx.x;
  if(i >= ET) return;
  int s = esrc[i], d = edst[i];
  float2 a = ((const float2*)asv)[s];
  float2 b = ((const float2*)adv)[d];
  float2 w;
  w.x = __expf(lrelu(a.x + b.x));
  w.y = __expf(lrelu(a.y + b.y));
  wbuf[i] = w;
}

// ---------- edge aggregation, layer 1 (scalarized unroll-8, no arrays!) ----------
__global__ __launch_bounds__(256) void agg1_kernel(const int* __restrict__ rowptr, const int* __restrict__ esrc,
                                                   const float2* __restrict__ wbuf, const float* __restrict__ xp,
                                                   const float* __restrict__ b1, float* __restrict__ h){
  int node = blockIdx.x*4 + (threadIdx.x>>6);
  int l = threadIdx.x & 63;
  if(node >= N_NODES) return;
  int beg = rowptr[node], end = rowptr[node+1];
  const float2* xpv = (const float2*)xp;
  float accx = 0.f, accy = 0.f, s0 = 0.f, s1 = 0.f;
  int n = end - beg;
  int nq = n & ~7;
  for(int q = 0; q < nq; q += 8){
    int e0 = esrc[beg+q+0], e1 = esrc[beg+q+1], e2 = esrc[beg+q+2], e3 = esrc[beg+q+3];
    int e4 = esrc[beg+q+4], e5 = esrc[beg+q+5], e6 = esrc[beg+q+6], e7 = esrc[beg+q+7];
    float2 w0 = wbuf[beg+q+0], w1 = wbuf[beg+q+1], w2 = wbuf[beg+q+2], w3 = wbuf[beg+q+3];
    float2 w4 = wbuf[beg+q+4], w5 = wbuf[beg+q+5], w6 = wbuf[beg+q+6], w7 = wbuf[beg+q+7];
    float2 x0 = xpv[(size_t)e0*64 + l], x1 = xpv[(size_t)e1*64 + l];
    float2 x2 = xpv[(size_t)e2*64 + l], x3 = xpv[(size_t)e3*64 + l];
    float2 x4 = xpv[(size_t)e4*64 + l], x5 = xpv[(size_t)e5*64 + l];
    float2 x6 = xpv[(size_t)e6*64 + l], x7 = xpv[(size_t)e7*64 + l];
    s0 += w0.x + w1.x + w2.x + w3.x + w4.x + w5.x + w6.x + w7.x;
    s1 += w0.y + w1.y + w2.y + w3.y + w4.y + w5.y + w6.y + w7.y;
    float v0 = (l < 32) ? w0.x : w0.y;
    float v1 = (l < 32) ? w1.x : w1.y;
    float v2 = (l < 32) ? w2.x : w2.y;
    float v3 = (l < 32) ? w3.x : w3.y;
    float v4 = (l < 32) ? w4.x : w4.y;
    float v5 = (l < 32) ? w5.x : w5.y;
    float v6 = (l < 32) ? w6.x : w6.y;
    float v7 = (l < 32) ? w7.x : w7.y;
    accx += v0*x0.x + v1*x1.x + v2*x2.x + v3*x3.x + v4*x4.x + v5*x5.x + v6*x6.x + v7*x7.x;
    accy += v0*x0.y + v1*x1.y + v2*x2.y + v3*x3.y + v4*x4.y + v5*x5.y + v6*x6.y + v7*x7.y;
  }
  for(int i = beg + nq; i < end; i++){
    int s = esrc[i];
    float2 w = wbuf[i];
    s0 += w.x; s1 += w.y;
    float2 xv = xpv[(size_t)s*64 + l];
    float ww = (l < 32) ? w.x : w.y;
    accx += ww * xv.x;
    accy += ww * xv.y;
  }
  float sd = (l < 32) ? s0 : s1;
  float2 bb = ((const float2*)b1)[l];
  float2 r;
  r.x = fmaxf(accx/sd + bb.x, 0.f);
  r.y = fmaxf(accy/sd + bb.y, 0.f);
  ((float2*)h)[(size_t)node*64 + l] = r;
}

// ---------- edge aggregation, layer 2 (mu+std fused; scalarized unroll-8) ----------
__global__ __launch_bounds__(256) void agg2_kernel(const int* __restrict__ rowptr, const int* __restrict__ esrc,
                                                   const float2* __restrict__ wbuf, const float* __restrict__ xp2,
                                                   const float* __restrict__ bmu, const float* __restrict__ bst,
                                                   float* __restrict__ out){
  int node = blockIdx.x*4 + (threadIdx.x>>6);
  int l = threadIdx.x & 63;
  if(node >= N_NODES) return;
  int half = l >> 5, c = l & 31;
  int beg = rowptr[node], end = rowptr[node+1];
  float acc = 0.f, ssum = 0.f;
  int n = end - beg;
  int nq = n & ~7;
  for(int q = 0; q < nq; q += 8){
    int e0 = esrc[beg+q+0], e1 = esrc[beg+q+1], e2 = esrc[beg+q+2], e3 = esrc[beg+q+3];
    int e4 = esrc[beg+q+4], e5 = esrc[beg+q+5], e6 = esrc[beg+q+6], e7 = esrc[beg+q+7];
    float2 w0 = wbuf[beg+q+0], w1 = wbuf[beg+q+1], w2 = wbuf[beg+q+2], w3 = wbuf[beg+q+3];
    float2 w4 = wbuf[beg+q+4], w5 = wbuf[beg+q+5], w6 = wbuf[beg+q+6], w7 = wbuf[beg+q+7];
    float x0 = xp2[(size_t)e0*64 + l], x1 = xp2[(size_t)e1*64 + l];
    float x2 = xp2[(size_t)e2*64 + l], x3 = xp2[(size_t)e3*64 + l];
    float x4 = xp2[(size_t)e4*64 + l], x5 = xp2[(size_t)e5*64 + l];
    float x6 = xp2[(size_t)e6*64 + l], x7 = xp2[(size_t)e7*64 + l];
    float v0 = half ? w0.y : w0.x;
    float v1 = half ? w1.y : w1.x;
    float v2 = half ? w2.y : w2.x;
    float v3 = half ? w3.y : w3.x;
    float v4 = half ? w4.y : w4.x;
    float v5 = half ? w5.y : w5.x;
    float v6 = half ? w6.y : w6.x;
    float v7 = half ? w7.y : w7.x;
    ssum += v0 + v1 + v2 + v3 + v4 + v5 + v6 + v7;
    acc  += v0*x0 + v1*x1 + v2*x2 + v3*x3 + v4*x4 + v5*x5 + v6*x6 + v7*x7;
  }
  for(int i = beg + nq; i < end; i++){
    int s = esrc[i];
    float2 w = wbuf[i];
    float ww = half ? w.y : w.x;
    ssum += ww;
    acc += ww * xp2[(size_t)s*64 + l];
  }
  float r = acc/ssum + (half ? bst[c] : bmu[c]);
  out[(half ? (size_t)N_NODES*Z : 0) + (size_t)node*Z + c] = r;
}

extern "C" void kernel_launch(void* const* d_in, const int* in_sizes, int n_in,
                              void* d_out, int out_size, void* d_ws, size_t ws_size,
                              hipStream_t stream){
  const float* x    = (const float*)d_in[0];
  const int*   edges= (const int*)d_in[1];
  const float* W1   = (const float*)d_in[2];
  const float* as1v = (const float*)d_in[3];
  const float* ad1v = (const float*)d_in[4];
  const float* b1   = (const float*)d_in[5];
  const float* Wmu  = (const float*)d_in[6];
  const float* asmu = (const float*)d_in[7];
  const float* admu = (const float*)d_in[8];
  const float* bmu  = (const float*)d_in[9];
  const float* Wst  = (const float*)d_in[10];
  const float* asst = (const float*)d_in[11];
  const float* adst = (const float*)d_in[12];
  const float* bst  = (const float*)d_in[13];
  float* out = (float*)d_out;

  char* p = (char*)d_ws;
  auto alloc = [&](size_t bytes)->char*{ char* r = p; p += (bytes + 255) & ~size_t(255); return r; };
  int*   deg    = (int*)  alloc((size_t)N_NODES*4);
  int*   rowptr = (int*)  alloc((size_t)(N_NODES+1)*4);
  int*   cursor = (int*)  alloc((size_t)N_NODES*4);
  int*   esrc   = (int*)  alloc((size_t)ET*4);
  int*   edst   = (int*)  alloc((size_t)ET*4);
  int*   bsum   = (int*)  alloc((size_t)NBS*4);
  int*   bpre   = (int*)  alloc((size_t)NBS*4);
  float* xp1    = (float*)alloc((size_t)N_NODES*128*4);
  float* as1    = (float*)alloc((size_t)N_NODES*2*4);
  float* ad1    = (float*)alloc((size_t)N_NODES*2*4);
  float* h      = (float*)alloc((size_t)N_NODES*128*4);
  float2* wbuf  = (float2*)alloc((size_t)ET*8);        // reused for layer 2
  float* as2    = (float*)alloc((size_t)N_NODES*2*4);
  float* ad2    = (float*)alloc((size_t)N_NODES*2*4);
  float* xp2    = xp1;                                  // xp1 dead after agg1

  hipMemsetAsync(deg, 0, (size_t)N_NODES*4, stream);
  hist_kernel   <<<(ET+255)/256, 256, 0, stream>>>(edges, deg);
  scan1_kernel  <<<NBS, 256, 0, stream>>>(deg, bsum);
  scan2_kernel  <<<1, 64, 0, stream>>>(bsum, bpre);
  scan3_kernel  <<<NBS, 256, 0, stream>>>(deg, bpre, rowptr, cursor);
  scatter_kernel<<<(ET+255)/256, 256, 0, stream>>>(edges, cursor, esrc, edst);

  mm_kernel<128,32><<<(N_NODES+31)/32, 256, 0, stream>>>(x, W1, W1, 128, xp1);
  alpha1_kernel<<<(N_NODES+3)/4, 256, 0, stream>>>(xp1, as1v, ad1v, as1, ad1);
  wcalc_kernel <<<(ET+255)/256, 256, 0, stream>>>(esrc, edst, as1, ad1, wbuf);
  agg1_kernel  <<<(N_NODES+3)/4, 256, 0, stream>>>(rowptr, esrc, wbuf, xp1, b1, h);

  mm_kernel<64,64><<<(N_NODES+63)/64, 256, 0, stream>>>(h, Wmu, Wst, 32, xp2);
  alpha2_kernel<<<(N_NODES+3)/4, 256, 0, stream>>>(xp2, asmu, admu, asst, adst, as2, ad2);
  wcalc_kernel <<<(ET+255)/256, 256, 0, stream>>>(esrc, edst, as2, ad2, wbuf);
  agg2_kernel  <<<(N_NODES+3)/4, 256, 0, stream>>>(rowptr, esrc, wbuf, xp2, bmu, bst, out);
}

// Round 6
// 369.089 us; speedup vs baseline: 1.1785x; 1.0781x over previous
//
#include <hip/hip_runtime.h>
#include <math.h>

#define N_NODES 50000
#define N_EDGES 800000
#define ET (N_EDGES + N_NODES)   // 850000 incl. self-loops
#define KD 128
#define Z 32
#define NBS ((N_NODES + 1023) / 1024)

static __device__ __forceinline__ float lrelu(float x){ return x > 0.f ? x : 0.2f*x; }
static __device__ __forceinline__ float bf2f(unsigned int u16){ return __uint_as_float(u16 << 16); }
static __device__ __forceinline__ unsigned short f2bf(float f){
  unsigned int x = __float_as_uint(f);
  return (unsigned short)((x + 0x7fffu + ((x >> 16) & 1u)) >> 16);   // RNE
}

// ---------- CSR build ----------
__global__ __launch_bounds__(256) void hist_kernel(const int* __restrict__ edges, int* __restrict__ deg){
  int k = blockIdx.x*256 + threadIdx.x;
  if(k >= ET) return;
  int d = (k < N_EDGES) ? edges[N_EDGES + k] : (k - N_EDGES);
  atomicAdd(&deg[d], 1);
}

__global__ __launch_bounds__(256) void scan1_kernel(const int* __restrict__ deg, int* __restrict__ bsum){
  int b = blockIdx.x, t = threadIdx.x;
  int base = b*1024 + t*4;
  int s = 0;
  #pragma unroll
  for(int i=0;i<4;i++){ int n = base+i; if(n < N_NODES) s += deg[n]; }
  for(int off=32; off; off>>=1) s += __shfl_xor(s, off);
  __shared__ int ws[4];
  if((t&63)==0) ws[t>>6] = s;
  __syncthreads();
  if(t==0) bsum[b] = ws[0]+ws[1]+ws[2]+ws[3];
}

__global__ __launch_bounds__(64) void scan2_kernel(const int* __restrict__ bsum, int* __restrict__ bpre){
  int t = threadIdx.x;
  int x = (t < NBS) ? bsum[t] : 0;
  int v = x;
  for(int off=1; off<64; off<<=1){
    int u = __shfl_up(v, off);
    if(t >= off) v += u;
  }
  if(t < NBS) bpre[t] = v - x;
}

__global__ __launch_bounds__(256) void scan3_kernel(const int* __restrict__ deg, const int* __restrict__ bpre,
                                                    int* __restrict__ rowptr, int* __restrict__ cursor){
  int b = blockIdx.x, t = threadIdx.x;
  int lane = t & 63, wv = t >> 6;
  int base = b*1024 + t*4;
  int d[4]; int s = 0;
  #pragma unroll
  for(int i=0;i<4;i++){ int n = base+i; d[i] = (n < N_NODES) ? deg[n] : 0; s += d[i]; }
  int v = s;
  for(int off=1; off<64; off<<=1){
    int u = __shfl_up(v, off);
    if(lane >= off) v += u;
  }
  int texcl = v - s;
  __shared__ int wtot[4];
  if(lane == 63) wtot[wv] = v;
  __syncthreads();
  int woff = 0;
  for(int i=0;i<wv;i++) woff += wtot[i];
  int run = bpre[b] + woff + texcl;
  #pragma unroll
  for(int i=0;i<4;i++){
    int n = base+i;
    if(n < N_NODES){ rowptr[n] = run; cursor[n] = run; run += d[i]; }
  }
  if(b == 0 && t == 0) rowptr[N_NODES] = ET;
}

__global__ __launch_bounds__(256) void scatter_kernel(const int* __restrict__ edges, int* __restrict__ cursor,
                                                      int* __restrict__ esrc, int* __restrict__ edst){
  int k = blockIdx.x*256 + threadIdx.x;
  if(k >= ET) return;
  int s, d;
  if(k < N_EDGES){ s = edges[k]; d = edges[N_EDGES+k]; } else { s = d = k - N_EDGES; }
  int pos = atomicAdd(&cursor[d], 1);
  esrc[pos] = s;
  edst[pos] = d;
}

// ---------- dense matmul: bf16 output (RNE), fp32 accumulate ----------
template<int OC, int NR>
__global__ __launch_bounds__(256) void mm_kernel(const float* __restrict__ X,
                                                 const float* __restrict__ Wa,
                                                 const float* __restrict__ Wb, int splitRow,
                                                 unsigned short* __restrict__ outb){
  constexpr int G  = OC/4;
  constexpr int RG = 256/G;
  static_assert(NR == RG*4, "rows per block mismatch");
  __shared__ __align__(16) float Wl[OC*KD];

  for(int idx = threadIdx.x; idx < OC*KD; idx += 256){
    int j = idx >> 7;
    int k = idx & 127;
    float v = (j < splitRow) ? Wa[j*KD + k] : Wb[(j-splitRow)*KD + k];
    int k4 = k >> 2, u = k & 3;
    Wl[j*KD + 4*(k4 ^ (j & 31)) + u] = v;
  }
  __syncthreads();

  int cx = threadIdx.x % G;
  int ry = threadIdx.x / G;
  int row0 = blockIdx.x * NR + ry*4;

  float acc[4][4];
  #pragma unroll
  for(int i=0;i<4;i++)
    #pragma unroll
    for(int j=0;j<4;j++) acc[i][j] = 0.f;

  for(int k4 = 0; k4 < KD/4; k4++){
    float4 xv[4];
    #pragma unroll
    for(int i=0;i<4;i++){
      int r = row0 + i; r = r < N_NODES ? r : N_NODES-1;
      xv[i] = *(const float4*)(X + (size_t)r*KD + 4*k4);
    }
    #pragma unroll
    for(int jj=0;jj<4;jj++){
      int c = cx + jj*G;
      float4 wv = *(const float4*)(&Wl[c*KD + 4*(k4 ^ (c & 31))]);
      #pragma unroll
      for(int i=0;i<4;i++){
        acc[i][jj] += xv[i].x*wv.x;
        acc[i][jj] += xv[i].y*wv.y;
        acc[i][jj] += xv[i].z*wv.z;
        acc[i][jj] += xv[i].w*wv.w;
      }
    }
  }

  #pragma unroll
  for(int i=0;i<4;i++){
    int r = row0 + i;
    if(r < N_NODES){
      #pragma unroll
      for(int jj=0;jj<4;jj++) outb[(size_t)r*OC + cx + jj*G] = f2bf(acc[i][jj]);
    }
  }
}

// ---------- attention coefficient dots (bf16 xp inputs, fp32 math) ----------
__global__ __launch_bounds__(256) void alpha1_kernel(const unsigned short* __restrict__ xpb,
                                                     const float* __restrict__ asv, const float* __restrict__ adv,
                                                     float* __restrict__ as1, float* __restrict__ ad1){
  int node = blockIdx.x*4 + (threadIdx.x>>6);
  int l = threadIdx.x & 63;
  if(node >= N_NODES) return;
  float x0 = bf2f(xpb[(size_t)node*128 + l]);
  float x1 = bf2f(xpb[(size_t)node*128 + 64 + l]);
  float s0 = x0*asv[l], s1 = x1*asv[64+l];
  float d0 = x0*adv[l], d1 = x1*adv[64+l];
  for(int off=32; off; off>>=1){
    s0 += __shfl_xor(s0, off); s1 += __shfl_xor(s1, off);
    d0 += __shfl_xor(d0, off); d1 += __shfl_xor(d1, off);
  }
  if(l == 0){ as1[node*2]=s0; as1[node*2+1]=s1; ad1[node*2]=d0; ad1[node*2+1]=d1; }
}

__global__ __launch_bounds__(256) void alpha2_kernel(const unsigned short* __restrict__ xpb2,
                                                     const float* __restrict__ asmu, const float* __restrict__ admu,
                                                     const float* __restrict__ asst, const float* __restrict__ adst,
                                                     float* __restrict__ as2, float* __restrict__ ad2){
  int node = blockIdx.x*4 + (threadIdx.x>>6);
  int l = threadIdx.x & 63;
  if(node >= N_NODES) return;
  int half = l >> 5, c = l & 31;
  float v = bf2f(xpb2[(size_t)node*64 + l]);
  float sp = v * (half ? asst[c] : asmu[c]);
  float dp = v * (half ? adst[c] : admu[c]);
  for(int off=16; off; off>>=1){ sp += __shfl_xor(sp, off); dp += __shfl_xor(dp, off); }
  if(c == 0){ as2[node*2+half] = sp; ad2[node*2+half] = dp; }
}

// ---------- per-edge softmax weights ----------
__global__ __launch_bounds__(256) void wcalc_kernel(const int* __restrict__ esrc, const int* __restrict__ edst,
                                                    const float* __restrict__ asv, const float* __restrict__ adv,
                                                    float2* __restrict__ wbuf){
  int i = blockIdx.x*256 + threadIdx.x;
  if(i >= ET) return;
  int s = esrc[i], d = edst[i];
  float2 a = ((const float2*)asv)[s];
  float2 b = ((const float2*)adv)[d];
  float2 w;
  w.x = __expf(lrelu(a.x + b.x));
  w.y = __expf(lrelu(a.y + b.y));
  wbuf[i] = w;
}

// ---------- edge aggregation, layer 1 (bf16 gathers, scalarized unroll-8) ----------
__global__ __launch_bounds__(256) void agg1_kernel(const int* __restrict__ rowptr, const int* __restrict__ esrc,
                                                   const float2* __restrict__ wbuf, const unsigned int* __restrict__ xb,
                                                   const float* __restrict__ b1, float* __restrict__ h){
  int node = blockIdx.x*4 + (threadIdx.x>>6);
  int l = threadIdx.x & 63;
  if(node >= N_NODES) return;
  int beg = rowptr[node], end = rowptr[node+1];
  float accx = 0.f, accy = 0.f, s0 = 0.f, s1 = 0.f;
  int n = end - beg;
  int nq = n & ~7;
  for(int q = 0; q < nq; q += 8){
    int e0 = esrc[beg+q+0], e1 = esrc[beg+q+1], e2 = esrc[beg+q+2], e3 = esrc[beg+q+3];
    int e4 = esrc[beg+q+4], e5 = esrc[beg+q+5], e6 = esrc[beg+q+6], e7 = esrc[beg+q+7];
    float2 w0 = wbuf[beg+q+0], w1 = wbuf[beg+q+1], w2 = wbuf[beg+q+2], w3 = wbuf[beg+q+3];
    float2 w4 = wbuf[beg+q+4], w5 = wbuf[beg+q+5], w6 = wbuf[beg+q+6], w7 = wbuf[beg+q+7];
    unsigned int u0 = xb[(size_t)e0*64 + l], u1 = xb[(size_t)e1*64 + l];
    unsigned int u2 = xb[(size_t)e2*64 + l], u3 = xb[(size_t)e3*64 + l];
    unsigned int u4 = xb[(size_t)e4*64 + l], u5 = xb[(size_t)e5*64 + l];
    unsigned int u6 = xb[(size_t)e6*64 + l], u7 = xb[(size_t)e7*64 + l];
    s0 += w0.x + w1.x + w2.x + w3.x + w4.x + w5.x + w6.x + w7.x;
    s1 += w0.y + w1.y + w2.y + w3.y + w4.y + w5.y + w6.y + w7.y;
    float v0 = (l < 32) ? w0.x : w0.y;
    float v1 = (l < 32) ? w1.x : w1.y;
    float v2 = (l < 32) ? w2.x : w2.y;
    float v3 = (l < 32) ? w3.x : w3.y;
    float v4 = (l < 32) ? w4.x : w4.y;
    float v5 = (l < 32) ? w5.x : w5.y;
    float v6 = (l < 32) ? w6.x : w6.y;
    float v7 = (l < 32) ? w7.x : w7.y;
    accx += v0*__uint_as_float(u0<<16) + v1*__uint_as_float(u1<<16)
          + v2*__uint_as_float(u2<<16) + v3*__uint_as_float(u3<<16)
          + v4*__uint_as_float(u4<<16) + v5*__uint_as_float(u5<<16)
          + v6*__uint_as_float(u6<<16) + v7*__uint_as_float(u7<<16);
    accy += v0*__uint_as_float(u0&0xffff0000u) + v1*__uint_as_float(u1&0xffff0000u)
          + v2*__uint_as_float(u2&0xffff0000u) + v3*__uint_as_float(u3&0xffff0000u)
          + v4*__uint_as_float(u4&0xffff0000u) + v5*__uint_as_float(u5&0xffff0000u)
          + v6*__uint_as_float(u6&0xffff0000u) + v7*__uint_as_float(u7&0xffff0000u);
  }
  for(int i = beg + nq; i < end; i++){
    int s = esrc[i];
    float2 w = wbuf[i];
    s0 += w.x; s1 += w.y;
    unsigned int u = xb[(size_t)s*64 + l];
    float ww = (l < 32) ? w.x : w.y;
    accx += ww * __uint_as_float(u<<16);
    accy += ww * __uint_as_float(u&0xffff0000u);
  }
  float sd = (l < 32) ? s0 : s1;
  float2 bb = ((const float2*)b1)[l];
  float2 r;
  r.x = fmaxf(accx/sd + bb.x, 0.f);
  r.y = fmaxf(accy/sd + bb.y, 0.f);
  ((float2*)h)[(size_t)node*64 + l] = r;
}

// ---------- edge aggregation, layer 2 (bf16 gathers; mu+std fused; unroll-8) ----------
__global__ __launch_bounds__(256) void agg2_kernel(const int* __restrict__ rowptr, const int* __restrict__ esrc,
                                                   const float2* __restrict__ wbuf, const unsigned short* __restrict__ xb2,
                                                   const float* __restrict__ bmu, const float* __restrict__ bst,
                                                   float* __restrict__ out){
  int node = blockIdx.x*4 + (threadIdx.x>>6);
  int l = threadIdx.x & 63;
  if(node >= N_NODES) return;
  int half = l >> 5, c = l & 31;
  int beg = rowptr[node], end = rowptr[node+1];
  float acc = 0.f, ssum = 0.f;
  int n = end - beg;
  int nq = n & ~7;
  for(int q = 0; q < nq; q += 8){
    int e0 = esrc[beg+q+0], e1 = esrc[beg+q+1], e2 = esrc[beg+q+2], e3 = esrc[beg+q+3];
    int e4 = esrc[beg+q+4], e5 = esrc[beg+q+5], e6 = esrc[beg+q+6], e7 = esrc[beg+q+7];
    float2 w0 = wbuf[beg+q+0], w1 = wbuf[beg+q+1], w2 = wbuf[beg+q+2], w3 = wbuf[beg+q+3];
    float2 w4 = wbuf[beg+q+4], w5 = wbuf[beg+q+5], w6 = wbuf[beg+q+6], w7 = wbuf[beg+q+7];
    float x0 = bf2f(xb2[(size_t)e0*64 + l]), x1 = bf2f(xb2[(size_t)e1*64 + l]);
    float x2 = bf2f(xb2[(size_t)e2*64 + l]), x3 = bf2f(xb2[(size_t)e3*64 + l]);
    float x4 = bf2f(xb2[(size_t)e4*64 + l]), x5 = bf2f(xb2[(size_t)e5*64 + l]);
    float x6 = bf2f(xb2[(size_t)e6*64 + l]), x7 = bf2f(xb2[(size_t)e7*64 + l]);
    float v0 = half ? w0.y : w0.x;
    float v1 = half ? w1.y : w1.x;
    float v2 = half ? w2.y : w2.x;
    float v3 = half ? w3.y : w3.x;
    float v4 = half ? w4.y : w4.x;
    float v5 = half ? w5.y : w5.x;
    float v6 = half ? w6.y : w6.x;
    float v7 = half ? w7.y : w7.x;
    ssum += v0 + v1 + v2 + v3 + v4 + v5 + v6 + v7;
    acc  += v0*x0 + v1*x1 + v2*x2 + v3*x3 + v4*x4 + v5*x5 + v6*x6 + v7*x7;
  }
  for(int i = beg + nq; i < end; i++){
    int s = esrc[i];
    float2 w = wbuf[i];
    float ww = half ? w.y : w.x;
    ssum += ww;
    acc += ww * bf2f(xb2[(size_t)s*64 + l]);
  }
  float r = acc/ssum + (half ? bst[c] : bmu[c]);
  out[(half ? (size_t)N_NODES*Z : 0) + (size_t)node*Z + c] = r;
}

extern "C" void kernel_launch(void* const* d_in, const int* in_sizes, int n_in,
                              void* d_out, int out_size, void* d_ws, size_t ws_size,
                              hipStream_t stream){
  const float* x    = (const float*)d_in[0];
  const int*   edges= (const int*)d_in[1];
  const float* W1   = (const float*)d_in[2];
  const float* as1v = (const float*)d_in[3];
  const float* ad1v = (const float*)d_in[4];
  const float* b1   = (const float*)d_in[5];
  const float* Wmu  = (const float*)d_in[6];
  const float* asmu = (const float*)d_in[7];
  const float* admu = (const float*)d_in[8];
  const float* bmu  = (const float*)d_in[9];
  const float* Wst  = (const float*)d_in[10];
  const float* asst = (const float*)d_in[11];
  const float* adst = (const float*)d_in[12];
  const float* bst  = (const float*)d_in[13];
  float* out = (float*)d_out;

  char* p = (char*)d_ws;
  auto alloc = [&](size_t bytes)->char*{ char* r = p; p += (bytes + 255) & ~size_t(255); return r; };
  int*   deg    = (int*)  alloc((size_t)N_NODES*4);
  int*   rowptr = (int*)  alloc((size_t)(N_NODES+1)*4);
  int*   cursor = (int*)  alloc((size_t)N_NODES*4);
  int*   esrc   = (int*)  alloc((size_t)ET*4);
  int*   edst   = (int*)  alloc((size_t)ET*4);
  int*   bsum   = (int*)  alloc((size_t)NBS*4);
  int*   bpre   = (int*)  alloc((size_t)NBS*4);
  unsigned short* xpb1 = (unsigned short*)alloc((size_t)N_NODES*128*2);  // bf16 projected features L1
  float* as1    = (float*)alloc((size_t)N_NODES*2*4);
  float* ad1    = (float*)alloc((size_t)N_NODES*2*4);
  float* h      = (float*)alloc((size_t)N_NODES*128*4);
  float2* wbuf  = (float2*)alloc((size_t)ET*8);        // reused for layer 2
  float* as2    = (float*)alloc((size_t)N_NODES*2*4);
  float* ad2    = (float*)alloc((size_t)N_NODES*2*4);
  unsigned short* xpb2 = xpb1;                          // xpb1 dead after agg1

  hipMemsetAsync(deg, 0, (size_t)N_NODES*4, stream);
  hist_kernel   <<<(ET+255)/256, 256, 0, stream>>>(edges, deg);
  scan1_kernel  <<<NBS, 256, 0, stream>>>(deg, bsum);
  scan2_kernel  <<<1, 64, 0, stream>>>(bsum, bpre);
  scan3_kernel  <<<NBS, 256, 0, stream>>>(deg, bpre, rowptr, cursor);
  scatter_kernel<<<(ET+255)/256, 256, 0, stream>>>(edges, cursor, esrc, edst);

  mm_kernel<128,32><<<(N_NODES+31)/32, 256, 0, stream>>>(x, W1, W1, 128, xpb1);
  alpha1_kernel<<<(N_NODES+3)/4, 256, 0, stream>>>(xpb1, as1v, ad1v, as1, ad1);
  wcalc_kernel <<<(ET+255)/256, 256, 0, stream>>>(esrc, edst, as1, ad1, wbuf);
  agg1_kernel  <<<(N_NODES+3)/4, 256, 0, stream>>>(rowptr, esrc, wbuf, (const unsigned int*)xpb1, b1, h);

  mm_kernel<64,64><<<(N_NODES+63)/64, 256, 0, stream>>>(h, Wmu, Wst, 32, xpb2);
  alpha2_kernel<<<(N_NODES+3)/4, 256, 0, stream>>>(xpb2, asmu, admu, asst, adst, as2, ad2);
  wcalc_kernel <<<(ET+255)/256, 256, 0, stream>>>(esrc, edst, as2, ad2, wbuf);
  agg2_kernel  <<<(N_NODES+3)/4, 256, 0, stream>>>(rowptr, esrc, wbuf, xpb2, bmu, bst, out);
}